// Round 1
// baseline (226.023 us; speedup 1.0000x reference)
//
#include <hip/hip_runtime.h>

#define EPS 1e-8f

using short8 = __attribute__((ext_vector_type(8))) short;
using f32x4  = __attribute__((ext_vector_type(4))) float;

__device__ __forceinline__ unsigned short f2bf(float f) {
    union { float f; unsigned u; } v; v.f = f;
    unsigned u = v.u;
    return (unsigned short)((u + 0x7FFFu + ((u >> 16) & 1u)) >> 16);
}

// ---------------- kernel 1: style[b][i] = dot(w[b], affine_w[i]) + affine_b[i] + 1
__global__ void style_kernel(const float* __restrict__ w,        // [8][512]
                             const float* __restrict__ affine_w, // [256][512]
                             const float* __restrict__ affine_b, // [256]
                             float* __restrict__ style) {        // [8][256]
    int b = blockIdx.x;
    int i = threadIdx.x;
    __shared__ float wb[512];
    for (int z = threadIdx.x; z < 512; z += 256) wb[z] = w[b * 512 + z];
    __syncthreads();
    const float* aw = affine_w + i * 512;
    float acc = 0.f;
#pragma unroll 4
    for (int z = 0; z < 512; z += 4) {
        float4 a4 = *reinterpret_cast<const float4*>(aw + z);
        acc += a4.x * wb[z] + a4.y * wb[z + 1] + a4.z * wb[z + 2] + a4.w * wb[z + 3];
    }
    style[b * 256 + i] = acc + affine_b[i] + 1.0f;
}

// ---------------- kernel 2: modulate + demodulate, pack bf16 weights
// wgt layout: bf16 [b][t(9)][g(32)][o(256)][j(8)], ic = g*8 + j
__global__ void modw_kernel(const float* __restrict__ weight, // [256][256][3][3]
                            const float* __restrict__ style,  // [8][256]
                            unsigned short* __restrict__ wgt) {
    int b = blockIdx.x >> 8;
    int o = blockIdx.x & 255;
    int ic = threadIdx.x; // 256 threads
    float s = style[b * 256 + ic];
    const float* wp = weight + (size_t)(o * 256 + ic) * 9;
    float m[9];
    float ss = 0.f;
#pragma unroll
    for (int t = 0; t < 9; ++t) { m[t] = wp[t] * s; ss += m[t] * m[t]; }
    // reduce over 256 threads
#pragma unroll
    for (int off = 32; off > 0; off >>= 1) ss += __shfl_down(ss, off);
    __shared__ float part[4];
    int lane = threadIdx.x & 63, wid = threadIdx.x >> 6;
    if (lane == 0) part[wid] = ss;
    __syncthreads();
    float denom = rsqrtf(part[0] + part[1] + part[2] + part[3] + EPS);
    int g = ic >> 3, j = ic & 7;
#pragma unroll
    for (int t = 0; t < 9; ++t) {
        size_t idx = ((((size_t)(b * 9 + t) * 32 + g) * 256 + o) << 3) + j;
        wgt[idx] = f2bf(m[t] * denom);
    }
}

// ---------------- kernel 3: implicit-GEMM conv via 16x16x32 bf16 MFMA
// block = (b, ot, h): 128 o-channels x 128 w-positions (one image row)
// K loop: 8 chunks of 32 input channels x 9 taps
__global__ __launch_bounds__(256, 2) void conv_kernel(
    const float* __restrict__ x,            // [8][256][128][128]
    const unsigned short* __restrict__ wgt, // packed bf16
    float* __restrict__ out) {              // [8][256][128][128]

    int bid = blockIdx.x;
    int h  = bid & 127;
    int ot = (bid >> 7) & 1;
    int b  = bid >> 8;

    __shared__ __align__(16) unsigned short Xs[3 * 4 * 130 * 8]; // 24960 B: [row][g][w130][j8]
    __shared__ __align__(16) unsigned short As[4 * 128 * 8];     // 8192 B:  [g][o128][j8]

    int tid  = threadIdx.x;
    int lane = tid & 63, wid = tid >> 6;
    int wm = wid >> 1, wn = wid & 1; // wave -> 64x64 subtile at (wm*64, wn*64)
    int l15 = lane & 15, lg = lane >> 4;

    f32x4 acc[4][4] = {};

    for (int c = 0; c < 8; ++c) {
        __syncthreads(); // prior phase done reading Xs/As
        // ---- stage X chunk: channels c*32..c*32+31, rows h-1..h+1, padded width 130
        for (int s = tid; s < 1560; s += 256) {
            int w_  = s % 130;
            int gg  = (s / 130) & 3;
            int row = s / 520;
            int hr = h + row - 1;
            int wi = w_ - 1;
            bool ok = ((unsigned)hr < 128u) && ((unsigned)wi < 128u);
            const float* xp = x + (((size_t)(b * 256 + c * 32 + gg * 8) * 128 + hr) * 128 + wi);
            union { unsigned short u[8]; short8 v; } pk;
#pragma unroll
            for (int j = 0; j < 8; ++j) {
                float f = ok ? xp[(size_t)j * 16384] : 0.f;
                pk.u[j] = f2bf(f);
            }
            *reinterpret_cast<short8*>(&Xs[s * 8]) = pk.v;
        }
        for (int t = 0; t < 9; ++t) {
            if (t) __syncthreads(); // prior tap done reading As
            // ---- stage A: 512 slots of 16B, coalesced
            {
                const unsigned short* ap =
                    wgt + ((((size_t)(b * 9 + t) * 32 + c * 4) * 256) + ot * 128) * 8;
#pragma unroll
                for (int s = tid; s < 512; s += 256) {
                    int g = s >> 7, ol = s & 127;
                    *reinterpret_cast<short8*>(&As[s * 8]) =
                        *reinterpret_cast<const short8*>(&ap[(g * 256 + ol) * 8]);
                }
            }
            __syncthreads();
            int kh = t / 3, kw = t % 3;
            short8 afrag[4], bfrag[4];
#pragma unroll
            for (int mi = 0; mi < 4; ++mi) {
                int ol = wm * 64 + mi * 16 + l15;
                afrag[mi] = *reinterpret_cast<const short8*>(&As[(lg * 128 + ol) * 8]);
            }
#pragma unroll
            for (int ni = 0; ni < 4; ++ni) {
                int wp = wn * 64 + ni * 16 + l15 + kw; // padded coord = n + kw
                bfrag[ni] = *reinterpret_cast<const short8*>(&Xs[(((kh * 4 + lg) * 130) + wp) * 8]);
            }
#pragma unroll
            for (int mi = 0; mi < 4; ++mi)
#pragma unroll
                for (int ni = 0; ni < 4; ++ni)
                    acc[mi][ni] = __builtin_amdgcn_mfma_f32_16x16x32_bf16(
                        afrag[mi], bfrag[ni], acc[mi][ni], 0, 0, 0);
        }
    }

    // ---- epilogue: C/D layout col=lane&15, row=(lane>>4)*4+r (m89-verified)
    int obase = ot * 128 + wm * 64;
#pragma unroll
    for (int mi = 0; mi < 4; ++mi) {
#pragma unroll
        for (int ni = 0; ni < 4; ++ni) {
            int o  = obase + mi * 16 + lg * 4;
            int w_ = wn * 64 + ni * 16 + l15;
            float* op = out + (((size_t)(b * 256 + o) * 128 + h) * 128 + w_);
#pragma unroll
            for (int r = 0; r < 4; ++r)
                op[(size_t)r * 16384] = acc[mi][ni][r];
        }
    }
}

extern "C" void kernel_launch(void* const* d_in, const int* in_sizes, int n_in,
                              void* d_out, int out_size, void* d_ws, size_t ws_size,
                              hipStream_t stream) {
    const float* x        = (const float*)d_in[0];
    const float* w        = (const float*)d_in[1];
    const float* weight   = (const float*)d_in[2];
    const float* affine_w = (const float*)d_in[3];
    const float* affine_b = (const float*)d_in[4];
    float* out = (float*)d_out;

    float* style = (float*)d_ws;                                   // 8 KB
    unsigned short* wgt = (unsigned short*)((char*)d_ws + 8192);   // 9.44 MB

    style_kernel<<<8, 256, 0, stream>>>(w, affine_w, affine_b, style);
    modw_kernel<<<2048, 256, 0, stream>>>(weight, style, wgt);
    conv_kernel<<<2048, 256, 0, stream>>>(x, wgt, out);
}

// Round 2
// 202.681 us; speedup vs baseline: 1.1152x; 1.1152x over previous
//
#include <hip/hip_runtime.h>

#define EPS 1e-8f

using short8 = __attribute__((ext_vector_type(8))) short;
using f32x4  = __attribute__((ext_vector_type(4))) float;
typedef unsigned short u16;

__device__ __forceinline__ u16 f2bf(float f) {
    union { float f; unsigned u; } v; v.f = f;
    unsigned u = v.u;
    return (u16)((u + 0x7FFFu + ((u >> 16) & 1u)) >> 16);
}

__device__ __forceinline__ void g2l16(const void* gsrc, void* ldst) {
    __builtin_amdgcn_global_load_lds(
        (const __attribute__((address_space(1))) unsigned int*)gsrc,
        (__attribute__((address_space(3))) unsigned int*)ldst, 16, 0, 0);
}

// ---------------- kernel 1: style[b][i] = dot(w[b], affine_w[i]) + affine_b[i] + 1
__global__ void style_kernel(const float* __restrict__ w,        // [8][512]
                             const float* __restrict__ affine_w, // [256][512]
                             const float* __restrict__ affine_b, // [256]
                             float* __restrict__ style) {        // [8][256]
    int b = blockIdx.x;
    int i = threadIdx.x;
    __shared__ float wb[512];
    for (int z = threadIdx.x; z < 512; z += 256) wb[z] = w[b * 512 + z];
    __syncthreads();
    const float* aw = affine_w + i * 512;
    float acc = 0.f;
#pragma unroll 4
    for (int z = 0; z < 512; z += 4) {
        float4 a4 = *reinterpret_cast<const float4*>(aw + z);
        acc += a4.x * wb[z] + a4.y * wb[z + 1] + a4.z * wb[z + 2] + a4.w * wb[z + 3];
    }
    style[b * 256 + i] = acc + affine_b[i] + 1.0f;
}

// ---------------- kernel 2: modulate + demodulate, pack bf16 weights
// wgt layout: bf16 [b][t(9)][g(32)][o(256)][j(8)], ic = g*8 + j
__global__ void modw_kernel(const float* __restrict__ weight, // [256][256][3][3]
                            const float* __restrict__ style,  // [8][256]
                            u16* __restrict__ wgt) {
    int b = blockIdx.x >> 8;
    int o = blockIdx.x & 255;
    int ic = threadIdx.x; // 256 threads
    float s = style[b * 256 + ic];
    const float* wp = weight + (size_t)(o * 256 + ic) * 9;
    float m[9];
    float ss = 0.f;
#pragma unroll
    for (int t = 0; t < 9; ++t) { m[t] = wp[t] * s; ss += m[t] * m[t]; }
#pragma unroll
    for (int off = 32; off > 0; off >>= 1) ss += __shfl_down(ss, off);
    __shared__ float part[4];
    int lane = threadIdx.x & 63, wid = threadIdx.x >> 6;
    if (lane == 0) part[wid] = ss;
    __syncthreads();
    float denom = rsqrtf(part[0] + part[1] + part[2] + part[3] + EPS);
    int g = ic >> 3, j = ic & 7;
#pragma unroll
    for (int t = 0; t < 9; ++t) {
        size_t idx = ((((size_t)(b * 9 + t) * 32 + g) * 256 + o) << 3) + j;
        wgt[idx] = f2bf(m[t] * denom);
    }
}

// ---------------- kernel 3: x fp32 [8][256][128][128] -> bf16 xb [8][32][128][128][8]
__global__ __launch_bounds__(256) void xform_kernel(const float* __restrict__ x,
                                                    u16* __restrict__ xb) {
    int s = blockIdx.x * 256 + threadIdx.x; // (b,g,h,w)
    int w = s & 127, h = (s >> 7) & 127, g = (s >> 14) & 31, b = s >> 19;
    const float* xp = x + (((size_t)(b * 256 + g * 8) * 128 + h) * 128 + w);
    union { u16 u[8]; short8 v; } pk;
#pragma unroll
    for (int j = 0; j < 8; ++j) pk.u[j] = f2bf(xp[(size_t)j * 16384]);
    *reinterpret_cast<short8*>(&xb[(size_t)s * 8]) = pk.v;
}

// ---------------- kernel 4: implicit-GEMM conv, 16x16x32 bf16 MFMA
// block = (b, ot, ht): 128 o x (2 rows x 128 w). K-loop: 8 chunks of 32 ic x 9 taps.
// X staged via global_load_lds (linear), A double-buffered (1 barrier/tap).
__global__ __launch_bounds__(256, 2) void conv_kernel(
    const u16* __restrict__ xb,  // [8][32][128][128][8] bf16
    const u16* __restrict__ wgt, // [8][9][32][256][8] bf16
    float* __restrict__ out) {   // [8][256][128][128]

    __shared__ __align__(16) u16 Xs[4][4][130][8];  // 33280 B: [row4][g][w130][j8]
    __shared__ __align__(16) u16 As[2][4][129][8];  // 16512 B: [buf][g][o128+pad][j8]

    int bid = blockIdx.x;
    int ht = bid & 63;
    int ot = (bid >> 6) & 1;
    int b  = bid >> 7;
    int h0 = ht * 2;

    int tid = threadIdx.x, lane = tid & 63, wid = tid >> 6;
    int wm = wid >> 1, wr = wid & 1; // wave -> (o half 64, row)
    int l15 = lane & 15, lg = lane >> 4;

    // zero Xs once (edge slots w=0,129 and out-of-range rows stay zero forever)
    {
        short8 z = {0, 0, 0, 0, 0, 0, 0, 0};
        short8* xz = reinterpret_cast<short8*>(&Xs[0][0][0][0]);
        for (int i = tid; i < 2080; i += 256) xz[i] = z;
    }

    f32x4 acc[4][8] = {};

    // stage helpers
    auto stageX = [&](int c) {
        // wave wid owns row r_=wid; 4 g x 2 halves = 8 segments of 1024B
        int hr = h0 + wid - 1;
        if ((unsigned)hr < 128u) {
#pragma unroll
            for (int k = 0; k < 8; ++k) {
                int g = k >> 1, half = k & 1;
                const u16* src = xb +
                    ((((size_t)(b * 32 + c * 4 + g) * 128 + hr) * 128) + half * 64 + lane) * 8;
                g2l16(src, &Xs[wid][g][1 + half * 64][0]);
            }
        }
    };
    auto stageA = [&](int nc, int nt, int nb) {
        // wave wid owns g=wid; 2 halves of 1024B
        const u16* base = wgt + ((((size_t)(b * 9 + nt) * 32) + nc * 4 + wid) * 256 + ot * 128) * 8;
        g2l16(base + (size_t)lane * 8, &As[nb][wid][0][0]);
        g2l16(base + (size_t)(64 + lane) * 8, &As[nb][wid][64][0]);
    };

    __syncthreads(); // Xs zero visible
    stageX(0);
    stageA(0, 0, 0);
    __syncthreads(); // drains vmcnt -> chunk0 + A(0,0) ready

    int cur = 0;
    for (int c = 0; c < 8; ++c) {
        for (int t = 0; t < 9; ++t) {
            bool lastPhase = (c == 7 && t == 8);
            if (!lastPhase) {
                int nt = t + 1, nc = c;
                if (nt == 9) { nt = 0; nc = c + 1; }
                stageA(nc, nt, cur ^ 1);
            }
            int kh = t / 3, kw = t - kh * 3;
            short8 af[4], bfv[8];
#pragma unroll
            for (int mi = 0; mi < 4; ++mi)
                af[mi] = *reinterpret_cast<const short8*>(&As[cur][lg][wm * 64 + mi * 16 + l15][0]);
#pragma unroll
            for (int ni = 0; ni < 8; ++ni)
                bfv[ni] = *reinterpret_cast<const short8*>(&Xs[wr + kh][lg][ni * 16 + l15 + kw][0]);
#pragma unroll
            for (int mi = 0; mi < 4; ++mi)
#pragma unroll
                for (int ni = 0; ni < 8; ++ni)
                    acc[mi][ni] = __builtin_amdgcn_mfma_f32_16x16x32_bf16(
                        af[mi], bfv[ni], acc[mi][ni], 0, 0, 0);
            if (t == 8 && c < 7) {
                __syncthreads();   // all waves done reading Xs chunk c
                stageX(c + 1);
            }
            if (!lastPhase) __syncthreads(); // A[next] + X[next] landed; readers of As[cur] done
            cur ^= 1;
        }
    }

    // epilogue: C/D layout col=lane&15 (w), row=(lane>>4)*4+r (o)
    int h = h0 + wr;
#pragma unroll
    for (int mi = 0; mi < 4; ++mi) {
        int o = ot * 128 + wm * 64 + mi * 16 + lg * 4;
#pragma unroll
        for (int ni = 0; ni < 8; ++ni) {
            int w_ = ni * 16 + l15;
            float* op = out + (((size_t)(b * 256 + o) * 128 + h) * 128 + w_);
#pragma unroll
            for (int r = 0; r < 4; ++r)
                op[(size_t)r * 16384] = acc[mi][ni][r];
        }
    }
}

extern "C" void kernel_launch(void* const* d_in, const int* in_sizes, int n_in,
                              void* d_out, int out_size, void* d_ws, size_t ws_size,
                              hipStream_t stream) {
    const float* x        = (const float*)d_in[0];
    const float* w        = (const float*)d_in[1];
    const float* weight   = (const float*)d_in[2];
    const float* affine_w = (const float*)d_in[3];
    const float* affine_b = (const float*)d_in[4];
    float* out = (float*)d_out;

    float* style = (float*)d_ws;                                   // 8 KB
    u16* wgt = (u16*)((char*)d_ws + 8192);                         // 9.44 MB
    u16* xbuf = (u16*)((char*)d_ws + 8192 + 9437184);              // 64 MB

    xform_kernel<<<16384, 256, 0, stream>>>(x, xbuf);
    style_kernel<<<8, 256, 0, stream>>>(w, affine_w, affine_b, style);
    modw_kernel<<<2048, 256, 0, stream>>>(weight, style, wgt);
    conv_kernel<<<1024, 256, 0, stream>>>(xbuf, wgt, out);
}